// Round 1
// baseline (287.698 us; speedup 1.0000x reference)
//
#include <hip/hip_runtime.h>

#define B_N 8192
#define C_N 20000
#define D_N 128
#define CPAD 20096              // 157 * 128
#define NTILE 157
#define MTILE 64
#define MARGIN_F 0.15001125f    // 0.15 + (1/40000)*(0.6-0.15)

typedef __attribute__((ext_vector_type(8))) short bf16x8;
typedef __attribute__((ext_vector_type(4))) float f32x4;

typedef __attribute__((address_space(1))) const unsigned int GUint;
typedef __attribute__((address_space(3))) unsigned int LUint;

__device__ __forceinline__ unsigned short f2bf(float x) {
    union { float f; unsigned int u; } v; v.f = x;
    unsigned int r = v.u + 0x7fffu + ((v.u >> 16) & 1u);
    return (unsigned short)(r >> 16);
}

// ---------------- kernel 1: L2-normalize features -> bf16, t[b] = MARGIN - posdot ----
__global__ __launch_bounds__(256) void k_normalize(
    const float* __restrict__ feat, const float* __restrict__ centers,
    const int* __restrict__ labels, unsigned short* __restrict__ fb,
    float* __restrict__ t)
{
    const int lane = threadIdx.x & 63;
    const int row  = blockIdx.x * 4 + (threadIdx.x >> 6);   // wave per row
    const float2 fv = *(const float2*)(feat + (size_t)row * D_N + lane * 2);
    float ss = fv.x * fv.x + fv.y * fv.y;
    #pragma unroll
    for (int off = 32; off; off >>= 1) ss += __shfl_xor(ss, off);
    const float scale = 1.0f / fmaxf(sqrtf(ss), 1e-12f);
    const float a = fv.x * scale, b = fv.y * scale;
    ushort2 o; o.x = f2bf(a); o.y = f2bf(b);
    *(ushort2*)(fb + (size_t)row * D_N + lane * 2) = o;
    const int lab = labels[row];
    const float2 cv = *(const float2*)(centers + (size_t)lab * D_N + lane * 2);
    float pd = a * cv.x + b * cv.y;
    #pragma unroll
    for (int off = 32; off; off >>= 1) pd += __shfl_xor(pd, off);
    if (lane == 0) t[row] = MARGIN_F - pd;
}

// ---------------- kernel 2: centers -> bf16, zero-pad rows [20000,20096) ----------
__global__ __launch_bounds__(256) void k_convert(
    const float* __restrict__ centers, unsigned short* __restrict__ cb)
{
    const int idx = blockIdx.x * 256 + threadIdx.x;   // one per 4 elements
    const int e = idx * 4;
    const int row = e >> 7;
    ushort4 o;
    if (row < C_N) {
        const float4 v = *(const float4*)(centers + e);
        o.x = f2bf(v.x); o.y = f2bf(v.y); o.z = f2bf(v.z); o.w = f2bf(v.w);
    } else {
        o.x = 0; o.y = 0; o.z = 0; o.w = 0;
    }
    *(ushort4*)(cb + e) = o;
}

// ---------------- kernel 3: main fused GEMM + masked mean reduction -------------
// 128x128 tile, 4 waves (2x2 of 64x64), K=128 staged once. bf16 16x16x32 MFMA.
__global__ __launch_bounds__(256, 2) void k_main(
    const unsigned short* __restrict__ fb,   // [8192][128] bf16, L2-normalized
    const unsigned short* __restrict__ cb,   // [20096][128] bf16, zero-padded
    const float* __restrict__ t,             // [8192]
    const int* __restrict__ labels,          // [8192]
    float* __restrict__ acc_total, unsigned int* __restrict__ acc_cnt)
{
    __shared__ unsigned short sA[128 * 128];   // 32 KB
    __shared__ unsigned short sB[128 * 128];   // 32 KB
    __shared__ int   sLab[128];
    __shared__ float sT[128];
    __shared__ float sWsum[4];
    __shared__ unsigned int sWcnt[4];

    const int tid  = threadIdx.x;
    const int lane = tid & 63;
    const int w    = tid >> 6;          // wave 0..3
    const int bn   = blockIdx.x;        // 0..156 col tiles
    const int bm   = blockIdx.y;        // 0..63  row tiles

    // stage labels + t for this row block
    if (tid < 128) {
        const int gr = bm * 128 + tid;
        sLab[tid] = labels[gr];
        sT[tid]   = t[gr];
    }

    // stage A and B tiles (each a contiguous 32KB global region) via
    // global_load_lds w=16. LDS dest linear; global SOURCE pre-swizzled with
    // the involution  sx = x ^ (((x>>8)&7)<<4)  so reads can use the same XOR.
    {
        const char* gA = (const char*)(fb + (size_t)bm * 128 * D_N);
        const char* gB = (const char*)(cb + (size_t)bn * 128 * D_N);
        const int chunk = w * 8192;
        #pragma unroll
        for (int i = 0; i < 8; ++i) {
            const int loff = chunk + i * 1024;          // wave-uniform LDS base
            const int x    = loff + lane * 16;          // this lane's LDS slot
            const int sx   = x ^ (((x >> 8) & 7) << 4); // swizzled source
            __builtin_amdgcn_global_load_lds((GUint*)(gA + sx),
                                             (LUint*)((char*)sA + loff), 16, 0, 0);
            __builtin_amdgcn_global_load_lds((GUint*)(gB + sx),
                                             (LUint*)((char*)sB + loff), 16, 0, 0);
        }
    }
    __syncthreads();   // compiler drains vmcnt before s_barrier

    // compute: wave (wm,wn) owns 64x64; 4x4 fragments of 16x16; K = 4 x 32
    const int wm = (w >> 1) * 64;
    const int wn = (w & 1) * 64;
    const int lrow = lane & 15;         // operand row within fragment
    const int kgrp = lane >> 4;         // k sub-block (8 bf16)

    f32x4 acc[4][4] = {};

    #pragma unroll
    for (int ks = 0; ks < 4; ++ks) {
        bf16x8 afr[4], bfr[4];
        #pragma unroll
        for (int fm = 0; fm < 4; ++fm) {
            const int row = wm + fm * 16 + lrow;
            int p = row * 256 + ks * 64 + kgrp * 16;
            p ^= ((row & 7) << 4);
            afr[fm] = *(const bf16x8*)((const char*)sA + p);
        }
        #pragma unroll
        for (int fn = 0; fn < 4; ++fn) {
            const int row = wn + fn * 16 + lrow;
            int p = row * 256 + ks * 64 + kgrp * 16;
            p ^= ((row & 7) << 4);
            bfr[fn] = *(const bf16x8*)((const char*)sB + p);
        }
        #pragma unroll
        for (int fm = 0; fm < 4; ++fm)
            #pragma unroll
            for (int fn = 0; fn < 4; ++fn)
                acc[fm][fn] = __builtin_amdgcn_mfma_f32_16x16x32_bf16(
                    afr[fm], bfr[fn], acc[fm][fn], 0, 0, 0);
    }

    // epilogue: loss = t[m] + dot ; mask ; accumulate
    float lsum = 0.0f;
    unsigned int lcnt = 0;
    const int crow0 = (lane >> 4) * 4;  // C/D: row=(lane>>4)*4+reg, col=lane&15
    const int ccol  = lane & 15;
    #pragma unroll
    for (int fm = 0; fm < 4; ++fm) {
        #pragma unroll
        for (int r = 0; r < 4; ++r) {
            const int mloc = wm + fm * 16 + crow0 + r;
            const float tv = sT[mloc];
            const int   lb = sLab[mloc];
            #pragma unroll
            for (int fn = 0; fn < 4; ++fn) {
                const int n = bn * 128 + wn + fn * 16 + ccol;
                const float loss = tv + acc[fm][fn][r];
                if (n < C_N && n != lb && loss > 0.0f) { lsum += loss; lcnt++; }
            }
        }
    }

    #pragma unroll
    for (int off = 32; off; off >>= 1) {
        lsum += __shfl_down(lsum, off);
        lcnt += __shfl_down(lcnt, off);
    }
    if (lane == 0) { sWsum[w] = lsum; sWcnt[w] = lcnt; }
    __syncthreads();
    if (tid == 0) {
        const float s = sWsum[0] + sWsum[1] + sWsum[2] + sWsum[3];
        const unsigned int c = sWcnt[0] + sWcnt[1] + sWcnt[2] + sWcnt[3];
        atomicAdd(acc_total, s);
        atomicAdd(acc_cnt, c);
    }
}

// ---------------- kernel 4: finalize ------------------------------------------
__global__ void k_finalize(const float* __restrict__ acc_total,
                           const unsigned int* __restrict__ acc_cnt,
                           float* __restrict__ out)
{
    const unsigned int c = *acc_cnt;
    out[0] = c ? (*acc_total / (float)c) : 0.0f;
}

extern "C" void kernel_launch(void* const* d_in, const int* in_sizes, int n_in,
                              void* d_out, int out_size, void* d_ws, size_t ws_size,
                              hipStream_t stream) {
    const float* feat    = (const float*)d_in[0];
    const float* centers = (const float*)d_in[1];
    const int*   labels  = (const int*)d_in[2];
    float* out = (float*)d_out;

    char* ws = (char*)d_ws;
    float*          acc_total = (float*)ws;              // 4 B
    unsigned int*   acc_cnt   = (unsigned int*)(ws + 4); // 4 B
    float*          t         = (float*)(ws + 256);                 // 32 KB
    unsigned short* fb        = (unsigned short*)(ws + 65536);      // 2 MB
    unsigned short* cb        = (unsigned short*)(ws + 4*1024*1024);// 5.14 MB

    hipMemsetAsync(ws, 0, 8, stream);
    k_normalize<<<B_N / 4, 256, 0, stream>>>(feat, centers, labels, fb, t);
    k_convert<<<(CPAD * D_N / 4) / 256, 256, 0, stream>>>(centers, cb);
    dim3 grid(NTILE, MTILE);
    k_main<<<grid, 256, 0, stream>>>(fb, cb, t, labels, acc_total, acc_cnt);
    k_finalize<<<1, 1, 0, stream>>>(acc_total, acc_cnt, out);
}

// Round 2
// 83.867 us; speedup vs baseline: 3.4304x; 3.4304x over previous
//
#include <hip/hip_runtime.h>

#define B_N 8192
#define C_N 20000
#define D_N 128
#define CPAD 20096              // 157 * 128
#define NTILES 157
#define NSPLIT 8
#define TPC 20                  // ceil(157/8) tiles per chunk
#define MARGIN_F 0.15001125f    // 0.15 + (1/40000)*(0.6-0.15)

typedef __attribute__((ext_vector_type(8))) short bf16x8;
typedef __attribute__((ext_vector_type(4))) float f32x4;

typedef __attribute__((address_space(1))) const unsigned int GUint;
typedef __attribute__((address_space(3))) unsigned int LUint;

__device__ __forceinline__ unsigned short f2bf(float x) {
    union { float f; unsigned int u; } v; v.f = x;
    unsigned int r = v.u + 0x7fffu + ((v.u >> 16) & 1u);
    return (unsigned short)(r >> 16);
}
__device__ __forceinline__ float bf2f(unsigned short h) {
    union { unsigned int u; float f; } v; v.u = ((unsigned int)h) << 16; return v.f;
}

// ---- kernel 1: normalize features -> bf16, t[b] = MARGIN - posdot, row corrections ----
// Correction per row b (subtracted in k_finalize):
//   label term:  loss_lab = t[b] + dot_bf16(f_b, c_lab)  (always counted in k_main)
//   pad columns: 96 zero-columns give loss = t[b] each (dot is exactly 0)
__global__ __launch_bounds__(256) void k_normalize(
    const float* __restrict__ feat, const float* __restrict__ centers,
    const int* __restrict__ labels, unsigned short* __restrict__ fb,
    float* __restrict__ t, float* __restrict__ corr_s, unsigned int* __restrict__ corr_c)
{
    const int lane = threadIdx.x & 63;
    const int row  = blockIdx.x * 4 + (threadIdx.x >> 6);   // wave per row
    const float2 fv = *(const float2*)(feat + (size_t)row * D_N + lane * 2);
    float ss = fv.x * fv.x + fv.y * fv.y;
    #pragma unroll
    for (int off = 32; off; off >>= 1) ss += __shfl_xor(ss, off);
    const float scale = 1.0f / fmaxf(sqrtf(ss), 1e-12f);
    const float a = fv.x * scale, b = fv.y * scale;
    ushort2 o; o.x = f2bf(a); o.y = f2bf(b);
    *(ushort2*)(fb + (size_t)row * D_N + lane * 2) = o;

    const int lab = labels[row];
    const float2 cv = *(const float2*)(centers + (size_t)lab * D_N + lane * 2);
    // fp32 positive dot (for t)
    float pd = a * cv.x + b * cv.y;
    // bf16-rounded dot (exactly what k_main's MFMA consumes, up to fp32 sum order)
    float pb = bf2f(o.x) * bf2f(f2bf(cv.x)) + bf2f(o.y) * bf2f(f2bf(cv.y));
    #pragma unroll
    for (int off = 32; off; off >>= 1) {
        pd += __shfl_xor(pd, off);
        pb += __shfl_xor(pb, off);
    }
    if (lane == 0) {
        const float tb = MARGIN_F - pd;
        t[row] = tb;
        float cs = fmaxf(tb + pb, 0.0f);            // label-column contribution
        unsigned int cc = (tb + pb > 0.0f) ? 1u : 0u;
        if (tb > 0.0f) { cs += 96.0f * tb; cc += 96u; }  // 96 padded columns
        corr_s[row] = cs;
        corr_c[row] = cc;
    }
}

// ---- kernel 2: centers -> bf16, zero-pad rows [20000,20096) ----
__global__ __launch_bounds__(256) void k_convert(
    const float* __restrict__ centers, unsigned short* __restrict__ cb)
{
    const int idx = blockIdx.x * 256 + threadIdx.x;
    const int e = idx * 4;
    const int row = e >> 7;
    ushort4 o;
    if (row < C_N) {
        const float4 v = *(const float4*)(centers + e);
        o.x = f2bf(v.x); o.y = f2bf(v.y); o.z = f2bf(v.z); o.w = f2bf(v.w);
    } else {
        o.x = 0; o.y = 0; o.z = 0; o.w = 0;
    }
    *(ushort4*)(cb + e) = o;
}

// ---- kernel 3: main. 256-row block, A in registers, B double-buffered LDS ----
// 8 waves (4x2), wave tile 64x64. acc initialized to t[m] so MFMA yields loss directly.
__global__ __launch_bounds__(512, 2) void k_main(
    const unsigned short* __restrict__ fb,   // [8192][128] bf16 normalized features
    const unsigned short* __restrict__ cb,   // [20096][128] bf16 centers, zero-padded
    const float* __restrict__ t,             // [8192]
    float* __restrict__ acc_total, unsigned int* __restrict__ acc_cnt)
{
    __shared__ unsigned short sB[2][128 * 128];   // 2 x 32 KB double buffer
    __shared__ float sWsum[8];
    __shared__ unsigned int sWcnt[8];

    const int tid  = threadIdx.x;
    const int lane = tid & 63;
    const int w    = tid >> 6;            // wave 0..7
    const int chunk  = blockIdx.x;        // 0..7  N chunks
    const int rowblk = blockIdx.y;        // 0..31 row blocks
    const int rowbase = rowblk * 256;
    const int t0 = chunk * TPC;
    const int nt = min(TPC, NTILES - t0);

    const int wm = (w >> 1) * 64;         // wave row offset (4 groups)
    const int wn = (w & 1) * 64;          // wave col offset (2 groups)
    const int lrow = lane & 15;
    const int kgrp = lane >> 4;

    // ---- prologue: A fragments -> registers (reused across all N tiles) ----
    bf16x8 afr[4][4];                     // [ks][fm]
    #pragma unroll
    for (int fm = 0; fm < 4; ++fm) {
        const unsigned short* src = fb + (size_t)(rowbase + wm + fm * 16 + lrow) * D_N + kgrp * 8;
        #pragma unroll
        for (int ks = 0; ks < 4; ++ks)
            afr[ks][fm] = *(const bf16x8*)(src + ks * 32);
    }
    // t values in C/D layout: row-in-frag = kgrp*4 + r
    float tvr[4][4];
    #pragma unroll
    for (int fm = 0; fm < 4; ++fm)
        #pragma unroll
        for (int r = 0; r < 4; ++r)
            tvr[fm][r] = t[rowbase + wm + fm * 16 + kgrp * 4 + r];

    // ---- B staging: both-sides swizzle, linear LDS dest + pre-swizzled source ----
    const char* gB0 = (const char*)cb;
    auto STAGE = [&](int buf, int tile) {
        const char* gB = gB0 + (size_t)tile * 32768;
        const int base = w * 4096;
        #pragma unroll
        for (int i = 0; i < 4; ++i) {
            const int loff = base + i * 1024;              // wave-uniform LDS base
            const int x = loff + lane * 16;
            const int sx = x ^ (((x >> 8) & 7) << 4);      // involution
            __builtin_amdgcn_global_load_lds((GUint*)(gB + sx),
                (LUint*)((char*)sB[buf] + loff), 16, 0, 0);
        }
    };

    STAGE(0, t0);
    __syncthreads();

    float lsum = 0.0f;
    unsigned int wcnt = 0;

    for (int j = 0; j < nt; ++j) {
        const int cur = j & 1;
        if (j + 1 < nt) STAGE(cur ^ 1, t0 + j + 1);        // prefetch next tile

        f32x4 acc[4][4];
        #pragma unroll
        for (int fm = 0; fm < 4; ++fm)
            #pragma unroll
            for (int fn = 0; fn < 4; ++fn)
                #pragma unroll
                for (int r = 0; r < 4; ++r)
                    acc[fm][fn][r] = tvr[fm][r];

        #pragma unroll
        for (int ks = 0; ks < 4; ++ks) {
            bf16x8 bfr[4];
            #pragma unroll
            for (int fn = 0; fn < 4; ++fn) {
                const int row = wn + fn * 16 + lrow;
                int p = row * 256 + ks * 64 + kgrp * 16;
                p ^= ((row & 7) << 4);
                bfr[fn] = *(const bf16x8*)((const char*)sB[cur] + p);
            }
            #pragma unroll
            for (int fm = 0; fm < 4; ++fm)
                #pragma unroll
                for (int fn = 0; fn < 4; ++fn)
                    acc[fm][fn] = __builtin_amdgcn_mfma_f32_16x16x32_bf16(
                        afr[ks][fm], bfr[fn], acc[fm][fn], 0, 0, 0);
        }

        // epilogue: 3 VALU/elem (max, add, cmp) + SALU popcount
        #pragma unroll
        for (int fm = 0; fm < 4; ++fm)
            #pragma unroll
            for (int fn = 0; fn < 4; ++fn)
                #pragma unroll
                for (int r = 0; r < 4; ++r) {
                    const float l = acc[fm][fn][r];
                    lsum += fmaxf(l, 0.0f);
                    wcnt += (unsigned int)__popcll(__ballot(l > 0.0f));
                }

        __syncthreads();   // prefetch landed; read buffer free for next stage
    }

    #pragma unroll
    for (int off = 32; off; off >>= 1) lsum += __shfl_xor(lsum, off);
    if (lane == 0) { sWsum[w] = lsum; sWcnt[w] = wcnt; }
    __syncthreads();
    if (tid == 0) {
        float s = 0.0f; unsigned int c = 0;
        #pragma unroll
        for (int i = 0; i < 8; ++i) { s += sWsum[i]; c += sWcnt[i]; }
        atomicAdd(acc_total, s);
        atomicAdd(acc_cnt, c);
    }
}

// ---- kernel 4: reduce corrections, finalize ----
__global__ __launch_bounds__(256) void k_finalize(
    const float* __restrict__ acc_total, const unsigned int* __restrict__ acc_cnt,
    const float* __restrict__ corr_s, const unsigned int* __restrict__ corr_c,
    float* __restrict__ out)
{
    __shared__ float ss[4];
    __shared__ unsigned int sc[4];
    const int tid = threadIdx.x;
    const int lane = tid & 63;
    const int w = tid >> 6;
    float cs = 0.0f; unsigned int cc = 0;
    for (int i = tid; i < B_N; i += 256) { cs += corr_s[i]; cc += corr_c[i]; }
    #pragma unroll
    for (int off = 32; off; off >>= 1) {
        cs += __shfl_xor(cs, off);
        cc += __shfl_xor(cc, off);
    }
    if (lane == 0) { ss[w] = cs; sc[w] = cc; }
    __syncthreads();
    if (tid == 0) {
        const float S = acc_total[0] - (ss[0] + ss[1] + ss[2] + ss[3]);
        const unsigned int C = acc_cnt[0] - (sc[0] + sc[1] + sc[2] + sc[3]);
        out[0] = C ? (S / (float)C) : 0.0f;
    }
}

extern "C" void kernel_launch(void* const* d_in, const int* in_sizes, int n_in,
                              void* d_out, int out_size, void* d_ws, size_t ws_size,
                              hipStream_t stream) {
    const float* feat    = (const float*)d_in[0];
    const float* centers = (const float*)d_in[1];
    const int*   labels  = (const int*)d_in[2];
    float* out = (float*)d_out;

    char* ws = (char*)d_ws;
    float*          acc_total = (float*)ws;                       // 4 B
    unsigned int*   acc_cnt   = (unsigned int*)(ws + 4);          // 4 B
    float*          t         = (float*)(ws + 1024);              // 32 KB
    float*          corr_s    = (float*)(ws + 65536);             // 32 KB
    unsigned int*   corr_c    = (unsigned int*)(ws + 98304);      // 32 KB
    unsigned short* fb        = (unsigned short*)(ws + 131072);   // 2 MB
    unsigned short* cb        = (unsigned short*)(ws + 4*1024*1024); // 5.14 MB

    hipMemsetAsync(ws, 0, 8, stream);
    k_normalize<<<B_N / 4, 256, 0, stream>>>(feat, centers, labels, fb, t, corr_s, corr_c);
    k_convert<<<(CPAD * D_N / 4) / 256, 256, 0, stream>>>(centers, cb);
    dim3 grid(NSPLIT, 32);
    k_main<<<grid, 512, 0, stream>>>(fb, cb, t, acc_total, acc_cnt);
    k_finalize<<<1, 256, 0, stream>>>(acc_total, acc_cnt, corr_s, corr_c, out);
}